// Round 4
// baseline (183.799 us; speedup 1.0000x reference)
//
#include <hip/hip_runtime.h>

// Performer (FAVOR+) causal linear attention — segment-persistent MFMA pipeline.
// B=4, H=16, L=2048, d_head=64, m=256, f32 in/out.

#define BB 4
#define HH 16
#define LL 2048
#define DH 64
#define DM 1024
#define MM 256
#define CC 64
#define NCH 32
#define SEGC 4          // chunks per segment
#define NSEG 8          // segments per slice

constexpr float SCALE = 0.17677669529663687f;  // 1024^-0.25
constexpr float NCF   = 0.0625f;               // 256^-0.5
constexpr float KEPS  = 1e-4f;
constexpr float NCFK  = NCF * KEPS;
constexpr float NSTB  = 1e-6f;

typedef __attribute__((ext_vector_type(8))) short s16x8;
typedef __attribute__((ext_vector_type(4))) float f32x4;

__device__ __forceinline__ float bf2f(unsigned short s) {
  return __uint_as_float(((unsigned)s) << 16);
}
__device__ __forceinline__ unsigned short f2bf(float f) {
  unsigned u = __float_as_uint(f);
  u += 0x7FFFu + ((u >> 16) & 1u);   // RNE
  return (unsigned short)(u >> 16);
}
__device__ __forceinline__ unsigned enc_key(float f) {
  unsigned u = __float_as_uint(f);
  return (u & 0x80000000u) ? ~u : (u | 0x80000000u);
}
__device__ __forceinline__ float dec_key(unsigned k) {
  unsigned u = (k & 0x80000000u) ? (k & 0x7FFFFFFFu) : ~k;
  return __uint_as_float(u);
}

// ---------------- k_stab = max over all rows of h_k ----------------
__global__ __launch_bounds__(256) void kstab_kernel(const float* __restrict__ Kin,
                                                    unsigned int* __restrict__ wsu) {
  int lane = threadIdx.x & 63;
  int wave = threadIdx.x >> 6;
  int base = blockIdx.x * 64 + wave * 16;
  float m = -3.4e38f;
  for (int it = 0; it < 16; ++it) {
    int r = base + it;
    float v = Kin[(size_t)r * 64 + lane];
    float s = v * v;
    #pragma unroll
    for (int off = 32; off; off >>= 1) s += __shfl_xor(s, off, 64);
    float hk = -0.5f * (SCALE * SCALE) * s;
    m = fmaxf(m, hk);
  }
  __shared__ float wmax[4];
  if (lane == 0) wmax[wave] = m;
  __syncthreads();
  if (threadIdx.x == 0) {
    float mm = fmaxf(fmaxf(wmax[0], wmax[1]), fmaxf(wmax[2], wmax[3]));
    atomicMax(wsu, enc_key(mm));
  }
}

// ---------------- RF prep: RFTg[m][d] bf16, row=128B, XOR-swizzled ----------------
__global__ __launch_bounds__(256) void rft_prep(const float* __restrict__ RF,
                                                unsigned short* __restrict__ RFTg) {
  int m = threadIdx.x;
  float rv[64];
  #pragma unroll
  for (int d = 0; d < 64; ++d) rv[d] = RF[d * MM + m];
  unsigned swz = (unsigned)((m & 7) << 4);
  #pragma unroll
  for (int c16 = 0; c16 < 8; ++c16) {
    union { unsigned short u[8]; uint4 v; } pk_;
    #pragma unroll
    for (int i = 0; i < 8; ++i) pk_.u[i] = f2bf(rv[c16 * 8 + i]);
    unsigned byte = (unsigned)(m * 128) + (((unsigned)(c16 * 16)) ^ swz);
    *(uint4*)((char*)RFTg + byte) = pk_.v;
  }
}

// ---------------- phase1: per-SEGMENT partial S^T (bf16 frag layout) + Z ----------------
// LDS: RFT 32K | KPmc 32K (2 halves) | VT 8K | Zw 4K  = 76K
__global__ __launch_bounds__(256, 2) void phase1_kernel(const float* __restrict__ Kin,
                                                        const float* __restrict__ Vin,
                                                        const unsigned short* __restrict__ RFTg,
                                                        unsigned short* __restrict__ wsSeg,
                                                        float* __restrict__ wsZ,
                                                        const unsigned int* __restrict__ wsu) {
  __shared__ __align__(16) char lds[77824];
  char* RFTl = lds;
  char* KPmc = lds + 32768;
  char* VT   = lds + 65536;
  float* Zw  = (float*)(lds + 73728);

  int slice = blockIdx.x / 7, seg = blockIdx.x % 7;
  int b = slice >> 4, h = slice & 15;
  const int t = threadIdx.x, lane = t & 63, w = t >> 6;
  const int rloc = lane & 15, kc0 = (lane >> 4) * 8;
  const unsigned lgrp16 = (unsigned)((lane >> 4) * 16);
  float kst = dec_key(*wsu);

  {  // RFT full copy (32 KB)
    const uint4* src = (const uint4*)RFTg;
    uint4* dst = (uint4*)RFTl;
    #pragma unroll
    for (int i = 0; i < 8; ++i) dst[t + 256 * i] = src[t + 256 * i];
  }
  #pragma unroll
  for (int i = 0; i < 4; ++i) Zw[t + 256 * i] = 0.f;

  f32x4 sacc[2][8];
  #pragma unroll
  for (int a = 0; a < 2; ++a)
    #pragma unroll
    for (int m = 0; m < 8; ++m) sacc[a][m] = (f32x4)0.f;

  for (int cc = 0; cc < SEGC; ++cc) {
    int c = seg * SEGC + cc;
    const int arow = 16 * w + rloc;
    const float* krow = Kin + ((size_t)(b * LL + c * CC + arow)) * DM + h * DH;
    s16x8 kfrag[2];
    float ss = 0.f;
    #pragma unroll
    for (int kf = 0; kf < 2; ++kf) {
      float4 ka_ = *(const float4*)(krow + kf * 32 + kc0);
      float4 kb_ = *(const float4*)(krow + kf * 32 + kc0 + 4);
      float ks[8] = {ka_.x, ka_.y, ka_.z, ka_.w, kb_.x, kb_.y, kb_.z, kb_.w};
      #pragma unroll
      for (int i = 0; i < 8; ++i) {
        float kv = ks[i] * SCALE;
        ss += kv * kv;
        kfrag[kf][i] = (short)f2bf(kv);
      }
    }
    ss += __shfl_xor(ss, 16, 64);
    ss += __shfl_xor(ss, 32, 64);
    float hkv = -0.5f * ss;
    float hk4[4];
    #pragma unroll
    for (int r = 0; r < 4; ++r) hk4[r] = __shfl(hkv, (lane >> 4) * 4 + r, 64);

    const float* vbase = Vin + ((size_t)(b * LL + c * CC + w * 16)) * DM + h * DH + lane;
    float vv[16];
    #pragma unroll
    for (int i = 0; i < 16; ++i) vv[i] = vbase[(size_t)i * DM];

    __syncthreads();  // B1: prior S-update reads of VT/KPmc done (also RFT/Zw init visible)
    {
      unsigned vswz = (unsigned)((lane & 7) << 4);
      #pragma unroll
      for (int q = 0; q < 2; ++q) {
        union { unsigned short u[8]; uint4 v; } pk_;
        #pragma unroll
        for (int i = 0; i < 8; ++i) pk_.u[i] = f2bf(vv[q * 8 + i]);
        unsigned byte = (unsigned)(lane * 128) + (((unsigned)(w * 32 + q * 16)) ^ vswz);
        *(uint4*)(VT + byte) = pk_.v;
      }
    }
    __syncthreads();  // B2

    #pragma unroll
    for (int h2 = 0; h2 < 2; ++h2) {
      #pragma unroll
      for (int mt = 0; mt < 8; ++mt) {
        int mloc = mt * 16 + rloc;
        unsigned rbyte = (unsigned)((h2 * 128 + mloc) * 128);
        unsigned swz = (unsigned)((mloc & 7) << 4);
        f32x4 pk = (f32x4)0.f;
        #pragma unroll
        for (int kf = 0; kf < 2; ++kf) {
          s16x8 bf_ = *(const s16x8*)(RFTl + rbyte + (((unsigned)(kf * 64) + lgrp16) ^ swz));
          pk = __builtin_amdgcn_mfma_f32_16x16x32_bf16(kfrag[kf], bf_, pk, 0, 0, 0);
        }
        float zp = 0.f;
        ushort4 kp4;
        #pragma unroll
        for (int r = 0; r < 4; ++r) {
          float kpv = NCF * __expf(hk4[r] + pk[r] - kst) + NCFK;
          zp += kpv;
          (&kp4.x)[r] = f2bf(kpv);
        }
        int cb = 16 * w + (lane >> 4) * 4;
        *(ushort4*)(KPmc + h2 * 16384 + mloc * 128 +
                    (((unsigned)(cb * 2)) ^ ((unsigned)((mloc & 7) << 4)))) = kp4;
        zp += __shfl_xor(zp, 16, 64);
        zp += __shfl_xor(zp, 32, 64);
        if (lane < 16) Zw[w * 256 + h2 * 128 + mt * 16 + lane] += zp;
      }
    }
    __syncthreads();  // B3

    s16x8 vt2[2];
    {
      int drow = w * 16 + rloc;
      unsigned rb = (unsigned)(drow * 128), sz = (unsigned)((drow & 7) << 4);
      #pragma unroll
      for (int kf = 0; kf < 2; ++kf)
        vt2[kf] = *(const s16x8*)(VT + rb + (((unsigned)(kf * 64) + lgrp16) ^ sz));
    }
    #pragma unroll
    for (int h2 = 0; h2 < 2; ++h2) {
      #pragma unroll
      for (int mt = 0; mt < 8; ++mt) {
        int mrow = mt * 16 + rloc;
        unsigned rb = (unsigned)(h2 * 16384 + mrow * 128);
        unsigned sz = (unsigned)((mrow & 7) << 4);
        #pragma unroll
        for (int kf = 0; kf < 2; ++kf) {
          s16x8 bf_ = *(const s16x8*)(KPmc + rb + (((unsigned)(kf * 64) + lgrp16) ^ sz));
          sacc[h2][mt] = __builtin_amdgcn_mfma_f32_16x16x32_bf16(vt2[kf], bf_, sacc[h2][mt], 0, 0, 0);
        }
      }
    }
  }

  // ---- write segment partial S (bf16, frag-flat layout, coalesced) ----
  {
    char* sb = (char*)wsSeg + (size_t)(slice * NSEG + seg) * 32768;
    #pragma unroll
    for (int j = 0; j < 8; ++j) {
      int h2 = j >> 2, m0 = (j & 3) * 2;
      union { unsigned short u[8]; uint4 v; } o;
      #pragma unroll
      for (int r = 0; r < 4; ++r) {
        o.u[r]     = f2bf(sacc[h2][m0][r]);
        o.u[4 + r] = f2bf(sacc[h2][m0 + 1][r]);
      }
      *(uint4*)(sb + (size_t)(j * 256 + t) * 16) = o.v;
    }
  }
  __syncthreads();
  float z = Zw[t] + Zw[256 + t] + Zw[512 + t] + Zw[768 + t];
  wsZ[(size_t)(slice * NSEG + seg) * 256 + t] = z;
}

// ---------------- phase2: exclusive prefix over segments (in-place) ----------------
__global__ __launch_bounds__(256) void scan_kernel(unsigned short* __restrict__ wsSeg,
                                                   float* __restrict__ wsZ) {
  int slice = blockIdx.x >> 2, part = blockIdx.x & 3;
  const int t = threadIdx.x;
  #pragma unroll
  for (int rep = 0; rep < 2; ++rep) {
    int g = part * 512 + rep * 256 + t;
    char* base = (char*)wsSeg + (size_t)slice * NSEG * 32768 + (size_t)g * 16;
    float run[8] = {0.f, 0.f, 0.f, 0.f, 0.f, 0.f, 0.f, 0.f};
    for (int s = 0; s < NSEG; ++s) {
      char* p = base + (size_t)s * 32768;
      uint4 x = make_uint4(0, 0, 0, 0);
      if (s < NSEG - 1) x = *(const uint4*)p;
      union { unsigned short u[8]; uint4 v; } o;
      #pragma unroll
      for (int i = 0; i < 8; ++i) o.u[i] = f2bf(run[i]);
      *(uint4*)p = o.v;
      const unsigned short* xu = (const unsigned short*)&x;
      #pragma unroll
      for (int i = 0; i < 8; ++i) run[i] += bf2f(xu[i]);
    }
  }
  if (part == 0) {
    float zr = 0.f;
    for (int s = 0; s < NSEG; ++s) {
      float* p = wsZ + ((size_t)slice * NSEG + s) * 256 + t;
      float x = (s < NSEG - 1) ? *p : 0.f;
      *p = zr;
      zr += x;
    }
  }
}

// ---------------- phase3: per-segment persistent outputs ----------------
// LDS: U0 16K (RFT-half / ST-half / Amask) | QP 16K | KPcm 16K | KPmc 16K | VT 8K | Zw 4K | ZL 1K
__global__ __launch_bounds__(256, 2) void phase3_kernel(const float* __restrict__ Qin,
                                                        const float* __restrict__ Kin,
                                                        const float* __restrict__ Vin,
                                                        const unsigned short* __restrict__ RFTg,
                                                        const unsigned short* __restrict__ wsSeg,
                                                        const float* __restrict__ wsZ,
                                                        const unsigned int* __restrict__ wsu,
                                                        float* __restrict__ Out) {
  __shared__ __align__(16) char lds[78848];
  char* U0   = lds;
  char* QP   = lds + 16384;
  char* KPcm = lds + 32768;
  char* KPmc = lds + 49152;
  char* VT   = lds + 65536;
  float* Zw  = (float*)(lds + 73728);
  float* ZL  = (float*)(lds + 77824);

  int slice = blockIdx.x >> 3, seg = blockIdx.x & 7;
  int b = slice >> 4, h = slice & 15;
  const int t = threadIdx.x, lane = t & 63, w = t >> 6;
  const int rloc = lane & 15, kc0 = (lane >> 4) * 8;
  const int arow = 16 * w + rloc;
  const unsigned lgrp16 = (unsigned)((lane >> 4) * 16);
  float kst = dec_key(*wsu);
  int slab = slice * NSEG + seg;

  ZL[t] = wsZ[(size_t)slab * 256 + t];

  f32x4 sacc[2][8];
  {
    const char* sb = (const char*)wsSeg + (size_t)slab * 32768;
    #pragma unroll
    for (int j = 0; j < 8; ++j) {
      uint4 x = *(const uint4*)(sb + (size_t)(j * 256 + t) * 16);
      const unsigned short* xu = (const unsigned short*)&x;
      int h2 = j >> 2, m0 = (j & 3) * 2;
      #pragma unroll
      for (int r = 0; r < 4; ++r) {
        sacc[h2][m0][r]     = bf2f(xu[r]);
        sacc[h2][m0 + 1][r] = bf2f(xu[4 + r]);
      }
    }
  }

  for (int cc = 0; cc < SEGC; ++cc) {
    int c = seg * SEGC + cc;
    const float* qrow = Qin + ((size_t)(b * LL + c * CC + arow)) * DM + h * DH;
    const float* krow = Kin + ((size_t)(b * LL + c * CC + arow)) * DM + h * DH;
    s16x8 qfrag[2], kfrag[2];
    float ss = 0.f;
    #pragma unroll
    for (int kf = 0; kf < 2; ++kf) {
      float4 qa_ = *(const float4*)(qrow + kf * 32 + kc0);
      float4 qb_ = *(const float4*)(qrow + kf * 32 + kc0 + 4);
      float4 ka_ = *(const float4*)(krow + kf * 32 + kc0);
      float4 kb_ = *(const float4*)(krow + kf * 32 + kc0 + 4);
      float qs[8] = {qa_.x, qa_.y, qa_.z, qa_.w, qb_.x, qb_.y, qb_.z, qb_.w};
      float ks[8] = {ka_.x, ka_.y, ka_.z, ka_.w, kb_.x, kb_.y, kb_.z, kb_.w};
      #pragma unroll
      for (int i = 0; i < 8; ++i) {
        float qv = qs[i] * SCALE, kv = ks[i] * SCALE;
        ss += kv * kv;
        qfrag[kf][i] = (short)f2bf(qv);
        kfrag[kf][i] = (short)f2bf(kv);
      }
    }
    ss += __shfl_xor(ss, 16, 64);
    ss += __shfl_xor(ss, 32, 64);
    float hkv = -0.5f * ss;
    float hk4[4];
    #pragma unroll
    for (int r = 0; r < 4; ++r) hk4[r] = __shfl(hkv, (lane >> 4) * 4 + r, 64);

    const float* vbase = Vin + ((size_t)(b * LL + c * CC + w * 16)) * DM + h * DH + lane;
    float vv[16];
    #pragma unroll
    for (int i = 0; i < 16; ++i) vv[i] = vbase[(size_t)i * DM];

    f32x4 Aacc[4], Oacc[4];
    #pragma unroll
    for (int i = 0; i < 4; ++i) { Aacc[i] = (f32x4)0.f; Oacc[i] = (f32x4)0.f; }
    float den1[4] = {0.f, 0.f, 0.f, 0.f};
    float den2[4] = {0.f, 0.f, 0.f, 0.f};

    for (int h2 = 0; h2 < 2; ++h2) {
      __syncthreads();  // B1: prior U0/VT readers done
      if (h2 == 0) {
        unsigned vswz = (unsigned)((lane & 7) << 4);
        #pragma unroll
        for (int q = 0; q < 2; ++q) {
          union { unsigned short u[8]; uint4 v; } pk_;
          #pragma unroll
          for (int i = 0; i < 8; ++i) pk_.u[i] = f2bf(vv[q * 8 + i]);
          unsigned byte = (unsigned)(lane * 128) + (((unsigned)(w * 32 + q * 16)) ^ vswz);
          *(uint4*)(VT + byte) = pk_.v;
        }
      }
      {  // RFT half -> U0
        const uint4* src = (const uint4*)RFTg + h2 * 1024;
        uint4* dst = (uint4*)U0;
        #pragma unroll
        for (int i = 0; i < 4; ++i) dst[t + 256 * i] = src[t + 256 * i];
      }
      __syncthreads();  // B2

      // ---- proj + exp fused per m-tile ----
      #pragma unroll
      for (int mt = 0; mt < 8; ++mt) {
        int mloc = mt * 16 + rloc;
        unsigned rbyte = (unsigned)(mloc * 128);
        unsigned swz = (unsigned)((mloc & 7) << 4);
        f32x4 pq = (f32x4)0.f, pk = (f32x4)0.f;
        #pragma unroll
        for (int kf = 0; kf < 2; ++kf) {
          s16x8 bf_ = *(const s16x8*)(U0 + rbyte + (((unsigned)(kf * 64) + lgrp16) ^ swz));
          pq = __builtin_amdgcn_mfma_f32_16x16x32_bf16(qfrag[kf], bf_, pq, 0, 0, 0);
          pk = __builtin_amdgcn_mfma_f32_16x16x32_bf16(kfrag[kf], bf_, pk, 0, 0, 0);
        }
        float zlv = ZL[h2 * 128 + mloc];
        float zp = 0.f;
        ushort4 kp4;
        #pragma unroll
        for (int r = 0; r < 4; ++r) {
          int row = 16 * w + (lane >> 4) * 4 + r;
          float qpv = NCF * __expf(pq[r]) + NCFK;
          float kpv = NCF * __expf(hk4[r] + pk[r] - kst) + NCFK;
          den2[r] += qpv * zlv;
          zp += kpv;
          (&kp4.x)[r] = f2bf(kpv);
          unsigned rswz = (unsigned)((row & 7) << 4);
          *(unsigned short*)(QP + row * 256 + (((unsigned)(mloc * 2)) ^ rswz)) = f2bf(qpv);
          *(unsigned short*)(KPcm + row * 256 + (((unsigned)(mloc * 2)) ^ rswz)) = f2bf(kpv);
        }
        int cb = 16 * w + (lane >> 4) * 4;
        *(ushort4*)(KPmc + mloc * 128 + (((unsigned)(cb * 2)) ^ ((unsigned)((mloc & 7) << 4)))) = kp4;
        zp += __shfl_xor(zp, 16, 64);
        zp += __shfl_xor(zp, 32, 64);
        if (lane < 16) Zw[w * 256 + h2 * 128 + mt * 16 + lane] = zp;
      }
      __syncthreads();  // B3

      s16x8 qa[4];
      {
        unsigned rb = (unsigned)(arow * 256), sz = (unsigned)((arow & 7) << 4);
        #pragma unroll
        for (int kf = 0; kf < 4; ++kf)
          qa[kf] = *(const s16x8*)(QP + rb + (((unsigned)(kf * 64) + lgrp16) ^ sz));
      }
      for (int ct = 0; ct <= w; ++ct) {
        int rowb = ct * 16 + rloc;
        unsigned rb = (unsigned)(rowb * 256), sz = (unsigned)((rowb & 7) << 4);
        #pragma unroll
        for (int kf = 0; kf < 4; ++kf) {
          s16x8 bf_ = *(const s16x8*)(KPcm + rb + (((unsigned)(kf * 64) + lgrp16) ^ sz));
          Aacc[ct] = __builtin_amdgcn_mfma_f32_16x16x32_bf16(qa[kf], bf_, Aacc[ct], 0, 0, 0);
        }
      }
      // snapshot S-half (pre-update) -> U0 (ST layout)
      #pragma unroll
      for (int mt = 0; mt < 8; ++mt) {
        int mloc = mt * 16 + rloc;
        #pragma unroll
        for (int r = 0; r < 4; ++r) {
          int d = 16 * w + (lane >> 4) * 4 + r;
          *(unsigned short*)(U0 + d * 256 +
                             (((unsigned)(mloc * 2)) ^ ((unsigned)((d & 7) << 4)))) =
              f2bf(sacc[h2][mt][r]);
        }
      }
      // S-update (register accumulators; skip on last chunk)
      if (cc != SEGC - 1) {
        s16x8 vt2[2];
        {
          int drow = w * 16 + rloc;
          unsigned rb = (unsigned)(drow * 128), sz = (unsigned)((drow & 7) << 4);
          #pragma unroll
          for (int kf = 0; kf < 2; ++kf)
            vt2[kf] = *(const s16x8*)(VT + rb + (((unsigned)(kf * 64) + lgrp16) ^ sz));
        }
        #pragma unroll
        for (int mt = 0; mt < 8; ++mt) {
          int mrow = mt * 16 + rloc;
          unsigned rb = (unsigned)(mrow * 128), sz = (unsigned)((mrow & 7) << 4);
          #pragma unroll
          for (int kf = 0; kf < 2; ++kf) {
            s16x8 bf_ = *(const s16x8*)(KPmc + rb + (((unsigned)(kf * 64) + lgrp16) ^ sz));
            sacc[h2][mt] = __builtin_amdgcn_mfma_f32_16x16x32_bf16(vt2[kf], bf_, sacc[h2][mt], 0, 0, 0);
          }
        }
      }
      __syncthreads();  // B4
      // O2: O += Qp * S_prev(half)
      #pragma unroll
      for (int ct = 0; ct < 4; ++ct) {
        int rowb = ct * 16 + rloc;
        unsigned rb = (unsigned)(rowb * 256), sz = (unsigned)((rowb & 7) << 4);
        #pragma unroll
        for (int kf = 0; kf < 4; ++kf) {
          s16x8 bf_ = *(const s16x8*)(U0 + rb + (((unsigned)(kf * 64) + lgrp16) ^ sz));
          Oacc[ct] = __builtin_amdgcn_mfma_f32_16x16x32_bf16(qa[kf], bf_, Oacc[ct], 0, 0, 0);
        }
      }
    }  // halves

    __syncthreads();  // B5: O2 reads done; Zw complete
    // mask A -> den1, Amask -> U0[0..8K)
    #pragma unroll
    for (int ct = 0; ct < 4; ++ct) {
      #pragma unroll
      for (int r = 0; r < 4; ++r) {
        int row = 16 * w + (lane >> 4) * 4 + r;
        int col = ct * 16 + rloc;
        float av = (ct <= w && col <= row) ? Aacc[ct][r] : 0.f;
        den1[r] += av;
        *(unsigned short*)(U0 + row * 128 +
                           (((unsigned)(col * 2)) ^ ((unsigned)((row & 7) << 4)))) = f2bf(av);
      }
    }
    if (cc != SEGC - 1) ZL[t] += Zw[t] + Zw[256 + t] + Zw[512 + t] + Zw[768 + t];
    __syncthreads();  // B6

    // O += mask(A) * V
    {
      int nkf = (w >= 2) ? 2 : 1;
      unsigned arb = (unsigned)(arow * 128), asz = (unsigned)((arow & 7) << 4);
      for (int kf = 0; kf < nkf; ++kf) {
        s16x8 af = *(const s16x8*)(U0 + arb + (((unsigned)(kf * 64) + lgrp16) ^ asz));
        #pragma unroll
        for (int ct = 0; ct < 4; ++ct) {
          int rowv = ct * 16 + rloc;
          s16x8 vf = *(const s16x8*)(VT + rowv * 128 +
                                     (((unsigned)(kf * 64) + lgrp16) ^ ((unsigned)((rowv & 7) << 4))));
          Oacc[ct] = __builtin_amdgcn_mfma_f32_16x16x32_bf16(af, vf, Oacc[ct], 0, 0, 0);
        }
      }
    }

    // denominator + epilogue
    float inv[4];
    #pragma unroll
    for (int r = 0; r < 4; ++r) {
      float dv = den1[r] + den2[r];
      dv += __shfl_xor(dv, 1, 64);
      dv += __shfl_xor(dv, 2, 64);
      dv += __shfl_xor(dv, 4, 64);
      dv += __shfl_xor(dv, 8, 64);
      if (fabsf(dv) <= NSTB) dv += 2.f * NSTB;
      inv[r] = 1.0f / dv;
    }
    #pragma unroll
    for (int r = 0; r < 4; ++r) {
      int row = 16 * w + (lane >> 4) * 4 + r;
      size_t g = ((size_t)(b * LL + c * CC + row)) * DM + h * DH;
      #pragma unroll
      for (int ct = 0; ct < 4; ++ct) {
        Out[g + ct * 16 + rloc] = Oacc[ct][r] * inv[r];
      }
    }
  }
}

extern "C" void kernel_launch(void* const* d_in, const int* in_sizes, int n_in,
                              void* d_out, int out_size, void* d_ws, size_t ws_size,
                              hipStream_t stream) {
  const float* Q  = (const float*)d_in[0];
  const float* K  = (const float*)d_in[1];
  const float* V  = (const float*)d_in[2];
  const float* RF = (const float*)d_in[3];
  float* Out = (float*)d_out;
  unsigned int* wsu = (unsigned int*)d_ws;

  const size_t RESV = 1024;
  const size_t RFTB = 32768;
  unsigned short* RFTg  = (unsigned short*)((char*)d_ws + RESV);
  unsigned short* wsSeg = (unsigned short*)((char*)d_ws + RESV + RFTB);
  float* wsZ = (float*)((char*)d_ws + RESV + RFTB + (size_t)64 * NSEG * 32768);
  // total: 1K + 32K + 16.78 MB + 512 KB ≈ 17.3 MB

  hipMemsetAsync(d_ws, 0, 4, stream);
  hipLaunchKernelGGL(kstab_kernel, dim3(2048), dim3(256), 0, stream, K, wsu);
  hipLaunchKernelGGL(rft_prep, dim3(1), dim3(256), 0, stream, RF, RFTg);
  hipLaunchKernelGGL(phase1_kernel, dim3(64 * 7), dim3(256), 0, stream,
                     K, V, RFTg, wsSeg, wsZ, wsu);
  hipLaunchKernelGGL(scan_kernel, dim3(256), dim3(256), 0, stream, wsSeg, wsZ);
  hipLaunchKernelGGL(phase3_kernel, dim3(64 * NSEG), dim3(256), 0, stream,
                     Q, K, V, RFTg, wsSeg, wsZ, wsu, Out);
}